// Round 4
// baseline (378.714 us; speedup 1.0000x reference)
//
#include <hip/hip_runtime.h>
#include <hip/hip_bf16.h>

// EmbeddingRNN via MFMA, round 4.
//   phase 0a: embW = emb @ W + b            (155 x 1024 f32, row-major)
//   phase 0b: Upack = U as bf16 MFMA B-fragments, 16-wave-slice-major
//   phase 1:  256 blocks x 16 waves x 32 rows, 16 steps fused.
//             Wave w owns d-slice [w*16, w*16+16) across all 4 gates -> 4 waves/SIMD
//             for latency hiding (R3 post-mortem: latency-bound at 2 waves/SIMD).
//             h kept f32 in LDS (XOR-swizzled), double-buffered, 1 barrier/step.
//             Next-step embW gather register-prefetched under the MFMA phase.

#define DD      256
#define G4      1024
#define NCHAR   155
#define TSTEPS  16
#define RTILE   32
#define NROWS   8192
#define NBLOCKS (NROWS / RTILE)   // 256
#define NTHREADS 1024             // 16 waves

typedef __attribute__((ext_vector_type(8))) short bf16x8;
typedef __attribute__((ext_vector_type(4))) float f32x4;

__device__ inline short f2bf(float f) {
    __hip_bfloat16 h = __float2bfloat16(f);   // RTNE
    return *reinterpret_cast<short*>(&h);
}

// ---------------- phase 0a: embW = emb @ W + b (row-major) ----------------
__global__ __launch_bounds__(256)
void embw_kernel(const float* __restrict__ emb, const float* __restrict__ W,
                 const float* __restrict__ b, float* __restrict__ embW) {
    const int i   = blockIdx.x;
    const int tid = threadIdx.x;
    float a0 = b[tid], a1 = b[256 + tid], a2 = b[512 + tid], a3 = b[768 + tid];
    const float* er = emb + i * DD;
    for (int k = 0; k < DD; ++k) {
        const float e = er[k];
        const float* wr = W + k * G4 + tid;
        a0 += e * wr[0];
        a1 += e * wr[256];
        a2 += e * wr[512];
        a3 += e * wr[768];
    }
    float* o = embW + i * G4 + tid;
    o[0] = a0; o[256] = a1; o[512] = a2; o[768] = a3;
}

// ---------------- phase 0b: pack U into bf16 MFMA B-fragments ----------------
// up[((w*8 + kt)*4 + g)*64 + lane]: lane l holds
//   U[kt*32 + (l>>4)*8 + j][g*256 + w*16 + (l&15)], j = 0..7
__global__ __launch_bounds__(256)
void upack_kernel(const float* __restrict__ U, bf16x8* __restrict__ up) {
    const int gid  = blockIdx.x * 256 + threadIdx.x;   // 32768 total
    const int lane = gid & 63;
    const int g    = (gid >> 6) & 3;
    const int kt   = (gid >> 8) & 7;
    const int w    = gid >> 11;
    const int col  = g * 256 + w * 16 + (lane & 15);
    const int k0   = kt * 32 + (lane >> 4) * 8;
    bf16x8 v;
#pragma unroll
    for (int j = 0; j < 8; ++j) v[j] = f2bf(U[(k0 + j) * G4 + col]);
    up[gid] = v;
}

// ---------------- phase 1: fused recurrence ----------------
__global__ __launch_bounds__(NTHREADS, 4)
void lstm_mfma(const int* __restrict__ x, const float* __restrict__ embW,
               const bf16x8* __restrict__ up, float* __restrict__ out) {
    // h f32, double-buffered, f32-index XOR swizzle ^((row&15)<<2)
    // (byte XOR (row&15)<<4): A-path ds_read_b128 at worst 2-way.
    __shared__ float hb[2][RTILE * DD];   // 2 x 32KB
    __shared__ int   xs[RTILE * TSTEPS];  // 2KB

    const int tid  = threadIdx.x;
    const int w    = tid >> 6;            // wave 0..15, owns d in [w*16, w*16+16)
    const int lane = tid & 63;
    const int l15  = lane & 15, lg = lane >> 4;
    const int base = blockIdx.x * RTILE;

    if (tid < RTILE * TSTEPS) xs[tid] = x[base * TSTEPS + tid];

    f32x4 acc[2][4];          // [mt][gate]
    float pre[2][4][4];       // [mt][j][gate] gather prefetch
    float c[2][4];            // [mt][j]
#pragma unroll
    for (int mt = 0; mt < 2; ++mt)
#pragma unroll
        for (int j = 0; j < 4; ++j) c[mt][j] = 0.f;

    const bf16x8* upw = up + w * 2048;    // this wave's 32KB packed U slice

    __syncthreads();

    // gather for t=0
#pragma unroll
    for (int mt = 0; mt < 2; ++mt)
#pragma unroll
        for (int j = 0; j < 4; ++j) {
            const int r    = mt * 16 + lg * 4 + j;
            const int xrow = xs[r * TSTEPS + 0];
            const float* e = embW + xrow * G4 + w * 16 + l15;
#pragma unroll
            for (int g = 0; g < 4; ++g) pre[mt][j][g] = e[g * 256];
        }

#pragma unroll 1
    for (int t = 0; t < TSTEPS; ++t) {
        // ---- acc init from prefetched gather ----
#pragma unroll
        for (int mt = 0; mt < 2; ++mt)
#pragma unroll
            for (int g = 0; g < 4; ++g)
#pragma unroll
                for (int j = 0; j < 4; ++j) acc[mt][g][j] = pre[mt][j][g];

        // ---- issue next step's gather (completes under MFMA phase) ----
        {
            const int tn = (t < TSTEPS - 1) ? t + 1 : TSTEPS - 1;
#pragma unroll
            for (int mt = 0; mt < 2; ++mt)
#pragma unroll
                for (int j = 0; j < 4; ++j) {
                    const int r    = mt * 16 + lg * 4 + j;
                    const int xrow = xs[r * TSTEPS + tn];
                    const float* e = embW + xrow * G4 + w * 16 + l15;
#pragma unroll
                    for (int g = 0; g < 4; ++g) pre[mt][j][g] = e[g * 256];
                }
        }

        // ---- z += h @ U via MFMA (skip at t=0: h=0) ----
        if (t > 0) {
            const float* rb = hb[(t - 1) & 1];
#pragma unroll
            for (int kt = 0; kt < 8; ++kt) {
                bf16x8 bfr[4];
#pragma unroll
                for (int g = 0; g < 4; ++g)
                    bfr[g] = upw[(kt * 4 + g) * 64 + lane];   // 1KB coalesced, L2

                bf16x8 afr[2];
#pragma unroll
                for (int mt = 0; mt < 2; ++mt) {
                    const int row = mt * 16 + l15;            // A row = lane&15
                    const int kb  = kt * 32 + lg * 8;         // A k = (lane>>4)*8+j
                    const int sw  = (row & 15) << 2;
                    const float4 f0 = *(const float4*)&rb[(row * DD + kb) ^ sw];
                    const float4 f1 = *(const float4*)&rb[(row * DD + kb + 4) ^ sw];
                    bf16x8 a;
                    a[0] = f2bf(f0.x); a[1] = f2bf(f0.y); a[2] = f2bf(f0.z); a[3] = f2bf(f0.w);
                    a[4] = f2bf(f1.x); a[5] = f2bf(f1.y); a[6] = f2bf(f1.z); a[7] = f2bf(f1.w);
                    afr[mt] = a;
                }
#pragma unroll
                for (int mt = 0; mt < 2; ++mt)
#pragma unroll
                    for (int g = 0; g < 4; ++g)
                        acc[mt][g] = __builtin_amdgcn_mfma_f32_16x16x32_bf16(
                            afr[mt], bfr[g], acc[mt][g], 0, 0, 0);
            }
        }

        // ---- gate update (Keras i,f,g,o; identity candidate/output) ----
        float* wb = hb[t & 1];
#pragma unroll
        for (int mt = 0; mt < 2; ++mt)
#pragma unroll
            for (int j = 0; j < 4; ++j) {
                const float zi = acc[mt][0][j];
                const float zf = acc[mt][1][j];
                const float zg = acc[mt][2][j];
                const float zo = acc[mt][3][j];
                const float ig = 1.f / (1.f + __expf(-zi));
                const float fg = 1.f / (1.f + __expf(-zf));
                const float og = 1.f / (1.f + __expf(-zo));
                const float cn = fg * c[mt][j] + ig * zg;
                c[mt][j] = cn;
                const float h = og * cn;
                const int row = mt * 16 + lg * 4 + j;
                const int d   = w * 16 + l15;
                wb[(row * DD + d) ^ ((row & 15) << 2)] = h;
                if (t == TSTEPS - 1) out[(base + row) * DD + d] = h;
            }
        __syncthreads();   // h(t) visible; prev-buffer reads done
    }
}

extern "C" void kernel_launch(void* const* d_in, const int* in_sizes, int n_in,
                              void* d_out, int out_size, void* d_ws, size_t ws_size,
                              hipStream_t stream) {
    const int*   x   = (const int*)d_in[0];
    const float* emb = (const float*)d_in[1];
    const float* W   = (const float*)d_in[2];
    const float* U   = (const float*)d_in[3];
    const float* b   = (const float*)d_in[4];
    float* out = (float*)d_out;

    float*  embW = (float*)d_ws;                          // 620KB
    bf16x8* up   = (bf16x8*)((char*)d_ws + (1 << 20));    // 512KB at +1MB

    embw_kernel<<<NCHAR, 256, 0, stream>>>(emb, W, b, embW);
    upack_kernel<<<128, 256, 0, stream>>>(U, up);
    lstm_mfma<<<NBLOCKS, NTHREADS, 0, stream>>>(x, embW, up, out);
}

// Round 5
// 323.600 us; speedup vs baseline: 1.1703x; 1.1703x over previous
//
#include <hip/hip_runtime.h>
#include <hip/hip_bf16.h>

// EmbeddingRNN via MFMA, round 5 = R2 skeleton + register-resident/pipelined B.
//   phase 0a: embWp = pack(emb @ W + b)  (155 x 1024 f32, packed for float4 gather)
//   phase 0b: Upack = U as bf16 MFMA B-fragments, 8-wave-slice-major
//   phase 1:  256 blocks x 8 waves x 32 rows, 16 steps fused.
//             kt=0 B-frags permanently in registers; kt=1..7 streamed through an
//             explicit 2-deep double-buffer (bA/bB, straight-line, no dyn indexing).
//             h f32 in LDS (XOR-swizzled), double-buffered, 1 barrier/step.

#define DD      256
#define G4      1024
#define NCHAR   155
#define TSTEPS  16
#define RTILE   32
#define NROWS   8192
#define NBLOCKS (NROWS / RTILE)   // 256
#define NTHREADS 512              // 8 waves; wave w owns d-slice [w*32, w*32+32)

typedef __attribute__((ext_vector_type(8))) short bf16x8;
typedef __attribute__((ext_vector_type(4))) float f32x4;

__device__ inline short f2bf(float f) {
    __hip_bfloat16 h = __float2bfloat16(f);   // RTNE
    return *reinterpret_cast<short*>(&h);
}

// ---------------- phase 0a: embWp = pack(emb @ W + b) ----------------
// value (char i, gate g, col d): w=d>>5, l15=d&15, nn=(d>>4)&1, nt=g*2+nn
// embWp[ ((i*8 + w)*16 + l15)*8 + nt ]
__global__ __launch_bounds__(256)
void embw_kernel(const float* __restrict__ emb, const float* __restrict__ W,
                 const float* __restrict__ b, float* __restrict__ embWp) {
    const int i   = blockIdx.x;
    const int tid = threadIdx.x;
    float a0 = b[tid], a1 = b[256 + tid], a2 = b[512 + tid], a3 = b[768 + tid];
    const float* er = emb + i * DD;
    for (int k = 0; k < DD; ++k) {
        const float e = er[k];
        const float* wr = W + k * G4 + tid;
        a0 += e * wr[0];
        a1 += e * wr[256];
        a2 += e * wr[512];
        a3 += e * wr[768];
    }
    const int w = tid >> 5, l15 = tid & 15, nn = (tid >> 4) & 1;
    float* o = embWp + ((i * 8 + w) * 16 + l15) * 8 + nn;
    o[0] = a0; o[2] = a1; o[4] = a2; o[6] = a3;   // nt = g*2+nn
}

// ---------------- phase 0b: pack U into bf16 MFMA B-fragments ----------------
// up[((w*8 + kt)*8 + nt)*64 + lane]: lane l holds
//   U[kt*32+(l>>4)*8+j][g*256 + w*32 + nn*16 + (l&15)], nt=g*2+nn
__global__ __launch_bounds__(256)
void upack_kernel(const float* __restrict__ U, bf16x8* __restrict__ up) {
    const int gid  = blockIdx.x * 256 + threadIdx.x;   // 32768 total
    const int lane = gid & 63;
    const int nt   = (gid >> 6) & 7;
    const int kt   = (gid >> 9) & 7;
    const int w    = gid >> 12;
    const int g = nt >> 1, nn = nt & 1;
    const int col = g * 256 + w * 32 + nn * 16 + (lane & 15);
    const int k0  = kt * 32 + (lane >> 4) * 8;
    bf16x8 v;
#pragma unroll
    for (int j = 0; j < 8; ++j) v[j] = f2bf(U[(k0 + j) * G4 + col]);
    up[gid] = v;
}

// ---------------- phase 1: fused recurrence ----------------

// load A-fragments (both mt) for K-tile KT from swizzled f32 LDS, then 16 MFMAs
#define AFR_MFMA(KT, BARR)                                                      \
    {                                                                           \
        bf16x8 afr0, afr1;                                                      \
        _Pragma("unroll")                                                       \
        for (int mt = 0; mt < 2; ++mt) {                                        \
            const int row = mt * 16 + l15;                                      \
            const int kb  = (KT) * 32 + lg * 8;                                 \
            const int sw  = (row & 15) << 2;                                    \
            const float4 f0 = *(const float4*)&rb[(row * DD + kb) ^ sw];        \
            const float4 f1 = *(const float4*)&rb[(row * DD + kb + 4) ^ sw];    \
            bf16x8 a;                                                           \
            a[0] = f2bf(f0.x); a[1] = f2bf(f0.y);                               \
            a[2] = f2bf(f0.z); a[3] = f2bf(f0.w);                               \
            a[4] = f2bf(f1.x); a[5] = f2bf(f1.y);                               \
            a[6] = f2bf(f1.z); a[7] = f2bf(f1.w);                               \
            if (mt == 0) afr0 = a; else afr1 = a;                               \
        }                                                                       \
        _Pragma("unroll")                                                       \
        for (int nt = 0; nt < 8; ++nt) {                                        \
            acc[0][nt] = __builtin_amdgcn_mfma_f32_16x16x32_bf16(               \
                afr0, (BARR)[nt], acc[0][nt], 0, 0, 0);                         \
            acc[1][nt] = __builtin_amdgcn_mfma_f32_16x16x32_bf16(               \
                afr1, (BARR)[nt], acc[1][nt], 0, 0, 0);                         \
        }                                                                       \
    }

#define LOADB(DST, KT)                                                          \
    _Pragma("unroll")                                                           \
    for (int nt = 0; nt < 8; ++nt) (DST)[nt] = upw[((KT) * 8 + nt) * 64 + lane];

__global__ __launch_bounds__(NTHREADS, 2)
void lstm_mfma(const int* __restrict__ x, const float* __restrict__ embWp,
               const bf16x8* __restrict__ up, float* __restrict__ out) {
    // h f32, double-buffered, f32-index XOR swizzle ^((row&15)<<2):
    // A-path ds_read_b128 at worst 2-way (free).
    __shared__ float hb[2][RTILE * DD];   // 2 x 32KB
    __shared__ int   xs[RTILE * TSTEPS];  // 2KB

    const int tid  = threadIdx.x;
    const int w    = tid >> 6;
    const int lane = tid & 63;
    const int l15  = lane & 15, lg = lane >> 4;
    const int base = blockIdx.x * RTILE;

    xs[tid] = x[base * TSTEPS + tid];

    f32x4 acc[2][8];
    float c[16];
#pragma unroll
    for (int i = 0; i < 16; ++i) c[i] = 0.f;

    const bf16x8* upw = up + w * 4096;    // this wave's 64KB packed U slice

    // kt=0 B-fragments: permanently register-resident (U is step-invariant)
    bf16x8 bres[8];
    LOADB(bres, 0);

    __syncthreads();

#pragma unroll 1
    for (int t = 0; t < TSTEPS; ++t) {
        bf16x8 bA[8], bB[8];
        // issue kt=1 loads first: they fly under the gather + kt=0 MFMAs
        if (t > 0) { LOADB(bA, 1); }

        // ---- acc init: z = embW[x_t] gather (+b folded), 2x float4/(mt,j) ----
#pragma unroll
        for (int mt = 0; mt < 2; ++mt) {
#pragma unroll
            for (int j = 0; j < 4; ++j) {
                const int r    = mt * 16 + lg * 4 + j;        // C/D row
                const int xrow = xs[r * TSTEPS + t];
                const float4* ew =
                    (const float4*)(embWp + ((xrow * 8 + w) * 16 + l15) * 8);
                const float4 g0 = ew[0];
                const float4 g1 = ew[1];
                acc[mt][0][j] = g0.x; acc[mt][1][j] = g0.y;
                acc[mt][2][j] = g0.z; acc[mt][3][j] = g0.w;
                acc[mt][4][j] = g1.x; acc[mt][5][j] = g1.y;
                acc[mt][6][j] = g1.z; acc[mt][7][j] = g1.w;
            }
        }

        // ---- z += h @ U via MFMA, 2-deep software pipeline over kt ----
        if (t > 0) {
            const float* rb = hb[(t - 1) & 1];
            AFR_MFMA(0, bres)                 // resident, starts immediately
            LOADB(bB, 2) AFR_MFMA(1, bA)
            LOADB(bA, 3) AFR_MFMA(2, bB)
            LOADB(bB, 4) AFR_MFMA(3, bA)
            LOADB(bA, 5) AFR_MFMA(4, bB)
            LOADB(bB, 6) AFR_MFMA(5, bA)
            LOADB(bA, 7) AFR_MFMA(6, bB)
            AFR_MFMA(7, bA)
        }

        // ---- gate update (Keras i,f,g,o; identity candidate/output) ----
        float* wb = hb[t & 1];
#pragma unroll
        for (int mt = 0; mt < 2; ++mt) {
#pragma unroll
            for (int nn = 0; nn < 2; ++nn) {
#pragma unroll
                for (int j = 0; j < 4; ++j) {
                    const float zi = acc[mt][0 + nn][j];
                    const float zf = acc[mt][2 + nn][j];
                    const float zg = acc[mt][4 + nn][j];
                    const float zo = acc[mt][6 + nn][j];
                    const float ig = 1.f / (1.f + __expf(-zi));
                    const float fg = 1.f / (1.f + __expf(-zf));
                    const float og = 1.f / (1.f + __expf(-zo));
                    const int   ci = mt * 8 + nn * 4 + j;
                    const float cn = fg * c[ci] + ig * zg;
                    c[ci] = cn;
                    const float h = og * cn;
                    const int row = mt * 16 + lg * 4 + j;
                    const int d   = w * 32 + nn * 16 + l15;
                    wb[(row * DD + d) ^ ((row & 15) << 2)] = h;
                    if (t == TSTEPS - 1) out[(base + row) * DD + d] = h;
                }
            }
        }
        __syncthreads();   // h(t) visible; prev-buffer reads done
    }
}

extern "C" void kernel_launch(void* const* d_in, const int* in_sizes, int n_in,
                              void* d_out, int out_size, void* d_ws, size_t ws_size,
                              hipStream_t stream) {
    const int*   x   = (const int*)d_in[0];
    const float* emb = (const float*)d_in[1];
    const float* W   = (const float*)d_in[2];
    const float* U   = (const float*)d_in[3];
    const float* b   = (const float*)d_in[4];
    float* out = (float*)d_out;

    float*  embWp = (float*)d_ws;                          // 620KB
    bf16x8* up    = (bf16x8*)((char*)d_ws + (1 << 20));    // 512KB at +1MB

    embw_kernel<<<NCHAR, 256, 0, stream>>>(emb, W, b, embWp);
    upack_kernel<<<128, 256, 0, stream>>>(U, up);
    lstm_mfma<<<NBLOCKS, NTHREADS, 0, stream>>>(x, embWp, up, out);
}